// Round 1
// baseline (372.917 us; speedup 1.0000x reference)
//
#include <hip/hip_runtime.h>
#include <hip/hip_bf16.h>
#include <stdint.h>

typedef __attribute__((ext_vector_type(8))) short short8;
typedef __attribute__((ext_vector_type(4))) short short4v;
typedef __attribute__((ext_vector_type(4))) float floatx4;

#define MFMA16(a, b, c) __builtin_amdgcn_mfma_f32_16x16x32_bf16((a), (b), (c), 0, 0, 0)

static __device__ __forceinline__ uint16_t f2bf(float f) {
  union { float f; uint32_t u; } x; x.f = f;
  uint32_t r = x.u + 0x7fffu + ((x.u >> 16) & 1u);
  return (uint16_t)(r >> 16);
}

constexpr int DM = 1024, NH = 16, KD = 64, NB = 2, SQ = 2048;
constexpr int MTOT = NB * SQ;  // 4096

// ---------------- kernel 1: fp32 -> bf16 convert ----------------
__global__ void convert_kernel(const float* __restrict__ X,
                               const float* __restrict__ Wq, const float* __restrict__ Wk,
                               const float* __restrict__ Wv, const float* __restrict__ Wo,
                               uint16_t* __restrict__ Xb, uint16_t* __restrict__ Wqkvb,
                               uint16_t* __restrict__ Wob) {
  const int NX = MTOT * DM;   // 4194304
  const int NW = DM * DM;     // 1048576
  const int TOT8 = (NX + 4 * NW) / 8;
  for (int t = blockIdx.x * blockDim.x + threadIdx.x; t < TOT8; t += gridDim.x * blockDim.x) {
    int i = t * 8;
    const float* src; uint16_t* dst;
    if (i < NX) { src = X + i; dst = Xb + i; }
    else if (i < NX + 3 * NW) {
      int j = i - NX; dst = Wqkvb + j;
      src = (j < NW) ? (Wq + j) : (j < 2 * NW) ? (Wk + (j - NW)) : (Wv + (j - 2 * NW));
    } else {
      int j = i - NX - 3 * NW; src = Wo + j; dst = Wob + j;
    }
    float4 a = ((const float4*)src)[0];
    float4 b = ((const float4*)src)[1];
    ushort4 o0, o1;
    o0.x = f2bf(a.x); o0.y = f2bf(a.y); o0.z = f2bf(a.z); o0.w = f2bf(a.w);
    o1.x = f2bf(b.x); o1.y = f2bf(b.y); o1.z = f2bf(b.z); o1.w = f2bf(b.w);
    ((ushort4*)dst)[0] = o0;
    ((ushort4*)dst)[1] = o1;
  }
}

// ---------------- kernel 2/4: 128x128 bf16 GEMM, C = A @ B^T ----------------
// A: [M][1024] bf16 row-major, B: [N][1024] bf16 row-major (B^T layout).
// MODE 0: QKV epilogue (scatter to Q (b,h,s,d) *0.125, K (b,h,s,d), V^T (b,h,d,s))
// MODE 1: plain fp32 store to Out[M][1024]
template <int MODE>
__global__ __launch_bounds__(256) void gemm_bt(const uint16_t* __restrict__ Aq,
                                               const uint16_t* __restrict__ Bq, int Ntiles,
                                               uint16_t* __restrict__ Qb, uint16_t* __restrict__ Kb,
                                               uint16_t* __restrict__ VTb, float* __restrict__ Out) {
  __shared__ uint16_t Al[128 * 32];
  __shared__ uint16_t Bl[128 * 32];
  const int K = 1024;
  int bid = blockIdx.x;
  int bm = bid / Ntiles, bn = bid % Ntiles;
  int brow = bm * 128, bcol = bn * 128;
  int tid = threadIdx.x;
  int w = tid >> 6, lane = tid & 63, g = lane >> 4, c16 = lane & 15;
  int wm = w >> 1, wn = w & 1;
  int rr = tid >> 2;            // 0..63 row within 64-row half-tile
  int ce = (tid & 3) * 8;       // col element (8 bf16 = 16B)

  floatx4 acc[4][4] = {};

  for (int k0 = 0; k0 < K; k0 += 32) {
    __syncthreads();
#pragma unroll
    for (int c = 0; c < 2; ++c) {
      __builtin_amdgcn_global_load_lds(
          (const __attribute__((address_space(1))) void*)(Aq + (size_t)(brow + c * 64 + rr) * K + k0 + ce),
          (__attribute__((address_space(3))) void*)((char*)Al + c * 4096 + w * 1024), 16, 0, 0);
      __builtin_amdgcn_global_load_lds(
          (const __attribute__((address_space(1))) void*)(Bq + (size_t)(bcol + c * 64 + rr) * K + k0 + ce),
          (__attribute__((address_space(3))) void*)((char*)Bl + c * 4096 + w * 1024), 16, 0, 0);
    }
    __syncthreads();
    short8 af[4], bf[4];
#pragma unroll
    for (int mt = 0; mt < 4; ++mt)
      af[mt] = *(const short8*)&Al[(wm * 64 + mt * 16 + c16) * 32 + g * 8];
#pragma unroll
    for (int nt = 0; nt < 4; ++nt)
      bf[nt] = *(const short8*)&Bl[(wn * 64 + nt * 16 + c16) * 32 + g * 8];
#pragma unroll
    for (int mt = 0; mt < 4; ++mt)
#pragma unroll
      for (int nt = 0; nt < 4; ++nt)
        acc[mt][nt] = MFMA16(af[mt], bf[nt], acc[mt][nt]);
  }

#pragma unroll
  for (int mt = 0; mt < 4; ++mt) {
#pragma unroll
    for (int nt = 0; nt < 4; ++nt) {
      int n = bcol + wn * 64 + nt * 16 + c16;
#pragma unroll
      for (int r = 0; r < 4; ++r) {
        int m = brow + wm * 64 + mt * 16 + g * 4 + r;
        float v = acc[mt][nt][r];
        if (MODE == 0) {
          int proj = n >> 10;
          int hd = n & 1023;
          int h = hd >> 6, d = hd & 63;
          int b = m >> 11, s = m & 2047;
          if (proj == 0) {
            Qb[((size_t)(b * NH + h) * SQ + s) * KD + d] = f2bf(v * 0.125f);  // fold 1/sqrt(64), exact
          } else if (proj == 1) {
            Kb[((size_t)(b * NH + h) * SQ + s) * KD + d] = f2bf(v);
          } else {
            VTb[((size_t)(b * NH + h) * KD + d) * SQ + s] = f2bf(v);
          }
        } else {
          Out[(size_t)m * DM + n] = v;
        }
      }
    }
  }
}

// ---------------- kernel 3: flash attention ----------------
// Q, K: (b,h,s,64) bf16 (Q pre-scaled by 0.125). VT: (b,h,64,s) bf16.
// O: (b,s,1024) bf16. Grid: (32 bh, 32 q-tiles), 256 threads (4 waves x 16 q-rows).
__global__ __launch_bounds__(256) void attn_kernel(const uint16_t* __restrict__ Q,
                                                   const uint16_t* __restrict__ Kb,
                                                   const uint16_t* __restrict__ VT,
                                                   uint16_t* __restrict__ O) {
  __shared__ __attribute__((aligned(16))) uint16_t Plds[4][16][68];  // pitch 68: conflict-free writes
  int bh = blockIdx.x;
  int qb = blockIdx.y * 64;
  int b = bh >> 4, h = bh & 15;
  int tid = threadIdx.x, w = tid >> 6, lane = tid & 63, g = lane >> 4, c16 = lane & 15;

  const uint16_t* Qh = Q + (size_t)bh * SQ * KD;
  const uint16_t* Kh = Kb + (size_t)bh * SQ * KD;
  const uint16_t* Vh = VT + (size_t)bh * KD * SQ;

  // Q fragments for this wave's 16 q-rows (A operand: row = lane&15, k = (lane>>4)*8+j)
  int qrow = qb + w * 16 + c16;
  short8 qf0 = *(const short8*)&Qh[(size_t)qrow * KD + g * 8];
  short8 qf1 = *(const short8*)&Qh[(size_t)qrow * KD + 32 + g * 8];

  float m4[4], l4[4];
  floatx4 accO[4] = {};
#pragma unroll
  for (int r = 0; r < 4; ++r) { m4[r] = -1e30f; l4[r] = 0.0f; }

  for (int kv0 = 0; kv0 < SQ; kv0 += 64) {
    // ---- S = Q @ K^T (4 tiles of 16 kv cols) ----
    floatx4 sacc[4] = {};
#pragma unroll
    for (int t = 0; t < 4; ++t) {
      short8 kf0 = *(const short8*)&Kh[(size_t)(kv0 + t * 16 + c16) * KD + g * 8];
      short8 kf1 = *(const short8*)&Kh[(size_t)(kv0 + t * 16 + c16) * KD + 32 + g * 8];
      sacc[t] = MFMA16(qf0, kf0, sacc[t]);
      sacc[t] = MFMA16(qf1, kf1, sacc[t]);
    }
    // D layout: kv-col = lane&15 (+16t), q-row = g*4+r
    // ---- online softmax (row reduce across 16 lanes sharing the q-row) ----
    float mloc[4];
#pragma unroll
    for (int r = 0; r < 4; ++r)
      mloc[r] = fmaxf(fmaxf(sacc[0][r], sacc[1][r]), fmaxf(sacc[2][r], sacc[3][r]));
#pragma unroll
    for (int off = 1; off < 16; off <<= 1)
#pragma unroll
      for (int r = 0; r < 4; ++r)
        mloc[r] = fmaxf(mloc[r], __shfl_xor(mloc[r], off));

    float alpha[4], rs[4], p[4][4];
#pragma unroll
    for (int r = 0; r < 4; ++r) {
      float nm = fmaxf(m4[r], mloc[r]);
      alpha[r] = __expf(m4[r] - nm);
      m4[r] = nm;
      float sum = 0.0f;
#pragma unroll
      for (int t = 0; t < 4; ++t) { p[t][r] = __expf(sacc[t][r] - nm); sum += p[t][r]; }
      rs[r] = sum;
    }
#pragma unroll
    for (int off = 1; off < 16; off <<= 1)
#pragma unroll
      for (int r = 0; r < 4; ++r)
        rs[r] += __shfl_xor(rs[r], off);
#pragma unroll
    for (int r = 0; r < 4; ++r)
      l4[r] = l4[r] * alpha[r] + rs[r];
#pragma unroll
    for (int dt = 0; dt < 4; ++dt)
#pragma unroll
      for (int r = 0; r < 4; ++r)
        accO[dt][r] *= alpha[r];

    // ---- P -> LDS ([q_local][kv_local], wave-private) ----
#pragma unroll
    for (int t = 0; t < 4; ++t)
#pragma unroll
      for (int r = 0; r < 4; ++r)
        Plds[w][g * 4 + r][c16 + 16 * t] = f2bf(p[t][r]);

    // ---- O += P @ V  (A-frag from LDS, B-frag = VT rows, contiguous) ----
#pragma unroll
    for (int c = 0; c < 2; ++c) {
      union { short8 s8; short4v s4[2]; } pu;
      pu.s4[0] = *(const short4v*)&Plds[w][c16][c * 32 + g * 8];
      pu.s4[1] = *(const short4v*)&Plds[w][c16][c * 32 + g * 8 + 4];
#pragma unroll
      for (int dt = 0; dt < 4; ++dt) {
        short8 vf = *(const short8*)&Vh[(size_t)(dt * 16 + c16) * SQ + kv0 + c * 32 + g * 8];
        accO[dt] = MFMA16(pu.s8, vf, accO[dt]);
      }
    }
  }

  // ---- normalize + store O in (b, s, h*64+d) layout ----
#pragma unroll
  for (int dt = 0; dt < 4; ++dt) {
#pragma unroll
    for (int r = 0; r < 4; ++r) {
      int s = qb + w * 16 + g * 4 + r;
      int d = dt * 16 + c16;
      float v = accO[dt][r] / l4[r];
      O[((size_t)(b * SQ + s)) * DM + h * KD + d] = f2bf(v);
    }
  }
}

// ---------------- launch ----------------
extern "C" void kernel_launch(void* const* d_in, const int* in_sizes, int n_in,
                              void* d_out, int out_size, void* d_ws, size_t ws_size,
                              hipStream_t stream) {
  const float* X = (const float*)d_in[0];
  const float* Wq = (const float*)d_in[1];
  const float* Wk = (const float*)d_in[2];
  const float* Wv = (const float*)d_in[3];
  const float* Wo = (const float*)d_in[4];
  float* out = (float*)d_out;

  char* ws = (char*)d_ws;
  uint16_t* Xb    = (uint16_t*)(ws);                 //  8 MiB  [4096][1024]
  uint16_t* Wqkvb = (uint16_t*)(ws + 8388608);       //  6 MiB  [3072][1024]
  uint16_t* Wob   = (uint16_t*)(ws + 14680064);      //  2 MiB  [1024][1024]
  uint16_t* Qb    = (uint16_t*)(ws + 16777216);      //  8 MiB  (b,h,s,d)
  uint16_t* Kb    = (uint16_t*)(ws + 25165824);      //  8 MiB  (b,h,s,d)
  uint16_t* VTb   = (uint16_t*)(ws + 33554432);      //  8 MiB  (b,h,d,s)
  uint16_t* Ob    = (uint16_t*)(ws + 41943040);      //  8 MiB  [4096][1024]

  hipLaunchKernelGGL(convert_kernel, dim3(1024), dim3(256), 0, stream,
                     X, Wq, Wk, Wv, Wo, Xb, Wqkvb, Wob);
  hipLaunchKernelGGL((gemm_bt<0>), dim3(32 * 24), dim3(256), 0, stream,
                     Xb, Wqkvb, 24, Qb, Kb, VTb, nullptr);
  hipLaunchKernelGGL(attn_kernel, dim3(32, 32), dim3(256), 0, stream,
                     Qb, Kb, VTb, Ob);
  hipLaunchKernelGGL((gemm_bt<1>), dim3(32 * 8), dim3(256), 0, stream,
                     Ob, Wob, 8, nullptr, nullptr, nullptr, out);
}

// Round 2
// 225.685 us; speedup vs baseline: 1.6524x; 1.6524x over previous
//
#include <hip/hip_runtime.h>
#include <hip/hip_bf16.h>
#include <stdint.h>

typedef __attribute__((ext_vector_type(8))) short short8;
typedef __attribute__((ext_vector_type(4))) float floatx4;

#define MFMA16(a, b, c) __builtin_amdgcn_mfma_f32_16x16x32_bf16((a), (b), (c), 0, 0, 0)

static __device__ __forceinline__ uint16_t f2bf(float f) {
  union { float f; uint32_t u; } x; x.f = f;
  uint32_t r = x.u + 0x7fffu + ((x.u >> 16) & 1u);
  return (uint16_t)(r >> 16);
}

constexpr int DM = 1024, NH = 16, KD = 64, NB = 2, SQ = 2048;
constexpr int MTOT = NB * SQ;  // 4096
constexpr int NT = SQ / 64;    // 32 kv tiles

// ---------------- kernel 1: fp32 -> bf16 convert ----------------
__global__ void convert_kernel(const float* __restrict__ X,
                               const float* __restrict__ Wq, const float* __restrict__ Wk,
                               const float* __restrict__ Wv, const float* __restrict__ Wo,
                               uint16_t* __restrict__ Xb, uint16_t* __restrict__ Wqkvb,
                               uint16_t* __restrict__ Wob) {
  const int NX = MTOT * DM;   // 4194304
  const int NW = DM * DM;     // 1048576
  const int TOT8 = (NX + 4 * NW) / 8;
  for (int t = blockIdx.x * blockDim.x + threadIdx.x; t < TOT8; t += gridDim.x * blockDim.x) {
    int i = t * 8;
    const float* src; uint16_t* dst;
    if (i < NX) { src = X + i; dst = Xb + i; }
    else if (i < NX + 3 * NW) {
      int j = i - NX; dst = Wqkvb + j;
      src = (j < NW) ? (Wq + j) : (j < 2 * NW) ? (Wk + (j - NW)) : (Wv + (j - 2 * NW));
    } else {
      int j = i - NX - 3 * NW; src = Wo + j; dst = Wob + j;
    }
    float4 a = ((const float4*)src)[0];
    float4 b = ((const float4*)src)[1];
    ushort4 o0, o1;
    o0.x = f2bf(a.x); o0.y = f2bf(a.y); o0.z = f2bf(a.z); o0.w = f2bf(a.w);
    o1.x = f2bf(b.x); o1.y = f2bf(b.y); o1.z = f2bf(b.z); o1.w = f2bf(b.w);
    ((ushort4*)dst)[0] = o0;
    ((ushort4*)dst)[1] = o1;
  }
}

// ---------------- kernel 2/4: 128x128 bf16 GEMM, C = A @ B^T ----------------
// MODE 0: QKV epilogue -> Q (bh,s,d)*0.125*log2e ; K blocked frag-linear ; V blocked frag-linear
// MODE 1: plain fp32 store to Out[M][1024]
template <int MODE>
__global__ __launch_bounds__(256) void gemm_bt(const uint16_t* __restrict__ Aq,
                                               const uint16_t* __restrict__ Bq, int Ntiles,
                                               uint16_t* __restrict__ Qb, uint16_t* __restrict__ Kb,
                                               uint16_t* __restrict__ VTb, float* __restrict__ Out) {
  __shared__ uint16_t Al[128 * 32];
  __shared__ uint16_t Bl[128 * 32];
  const int K = 1024;
  int bid = blockIdx.x;
  int bm = bid / Ntiles, bn = bid % Ntiles;
  int brow = bm * 128, bcol = bn * 128;
  int tid = threadIdx.x;
  int w = tid >> 6, lane = tid & 63, g = lane >> 4, c16 = lane & 15;
  int wm = w >> 1, wn = w & 1;
  int rr = tid >> 2;            // 0..63 row within 64-row half-tile
  int ce = (tid & 3) * 8;       // col element (8 bf16 = 16B)

  floatx4 acc[4][4] = {};

  for (int k0 = 0; k0 < K; k0 += 32) {
    __syncthreads();
#pragma unroll
    for (int c = 0; c < 2; ++c) {
      __builtin_amdgcn_global_load_lds(
          (const __attribute__((address_space(1))) void*)(Aq + (size_t)(brow + c * 64 + rr) * K + k0 + ce),
          (__attribute__((address_space(3))) void*)((char*)Al + c * 4096 + w * 1024), 16, 0, 0);
      __builtin_amdgcn_global_load_lds(
          (const __attribute__((address_space(1))) void*)(Bq + (size_t)(bcol + c * 64 + rr) * K + k0 + ce),
          (__attribute__((address_space(3))) void*)((char*)Bl + c * 4096 + w * 1024), 16, 0, 0);
    }
    __syncthreads();
    short8 af[4], bf[4];
#pragma unroll
    for (int mt = 0; mt < 4; ++mt)
      af[mt] = *(const short8*)&Al[(wm * 64 + mt * 16 + c16) * 32 + g * 8];
#pragma unroll
    for (int nt = 0; nt < 4; ++nt)
      bf[nt] = *(const short8*)&Bl[(wn * 64 + nt * 16 + c16) * 32 + g * 8];
#pragma unroll
    for (int mt = 0; mt < 4; ++mt)
#pragma unroll
      for (int nt = 0; nt < 4; ++nt)
        acc[mt][nt] = MFMA16(af[mt], bf[nt], acc[mt][nt]);
  }

#pragma unroll
  for (int mt = 0; mt < 4; ++mt) {
#pragma unroll
    for (int nt = 0; nt < 4; ++nt) {
      int n = bcol + wn * 64 + nt * 16 + c16;
#pragma unroll
      for (int r = 0; r < 4; ++r) {
        int m = brow + wm * 64 + mt * 16 + g * 4 + r;
        float v = acc[mt][nt][r];
        if (MODE == 0) {
          int proj = n >> 10;
          int hd = n & 1023;
          int h = hd >> 6, d = hd & 63;
          int b = m >> 11, s = m & 2047;
          size_t bh = (size_t)(b * NH + h);
          if (proj == 0) {
            // fold 1/sqrt(64) * log2(e) so attention can use exp2 directly
            Qb[(bh * SQ + s) * KD + d] = f2bf(v * 0.18033688011112042f);
          } else if (proj == 1) {
            // K blocked: [bh][st=s>>4][k8=d>>3][r=s&15][j=d&7]
            int st = s >> 4, r2 = s & 15, k8 = d >> 3, j = d & 7;
            Kb[bh * (size_t)(SQ * KD) + (((size_t)(st * 8 + k8) * 16 + r2) * 8 + j)] = f2bf(v);
          } else {
            // V blocked per 64-kv tile: [kt][c][dt][g][c16][jj]
            int kt = s >> 6, kvl = s & 63;
            int c = kvl >> 5, gg = (kvl >> 3) & 3, jj = kvl & 7;
            int dt = d >> 4, cc = d & 15;
            VTb[bh * (size_t)(SQ * KD) + (size_t)kt * 4096 +
                (size_t)(((((c * 4 + dt) * 4 + gg) * 16) + cc) * 8 + jj)] = f2bf(v);
          }
        } else {
          Out[(size_t)m * DM + n] = v;
        }
      }
    }
  }
}

// ---------------- kernel 3: flash attention (swapped QK^T, in-reg softmax) ----------------
// Q: (bh,s,64) bf16 pre-scaled by 0.125*log2e. K,V: blocked frag-linear per 64-kv tile.
// Grid: 1024 blocks (bh = bid&31 for XCD locality), 256 threads = 4 waves x 16 q-rows.
__global__ __launch_bounds__(256, 4) void attn_kernel(const uint16_t* __restrict__ Q,
                                                      const uint16_t* __restrict__ Kt,
                                                      const uint16_t* __restrict__ Vt,
                                                      uint16_t* __restrict__ O) {
  __shared__ __attribute__((aligned(16))) uint16_t Kbuf[2][4096];   // 2 x 8KB, frag-linear
  __shared__ __attribute__((aligned(16))) uint16_t Plds[4][16][72]; // pitch 72: 16B-aligned rows

  int bid = blockIdx.x;
  int bh = bid & 31, qt = bid >> 5;   // bid%8 == bh%8 -> same-head blocks share an XCD L2
  int qb = qt * 64;
  int b = bh >> 4, h = bh & 15;
  int tid = threadIdx.x, w = tid >> 6, lane = tid & 63, g = lane >> 4, c16 = lane & 15;

  const uint16_t* Qh = Q + (size_t)bh * SQ * KD;
  const uint16_t* Kh = Kt + (size_t)bh * SQ * KD;
  const uint16_t* Vh = Vt + (size_t)bh * SQ * KD;

  int qrow = qb + w * 16 + c16;
  short8 qf0 = *(const short8*)&Qh[(size_t)qrow * KD + g * 8];
  short8 qf1 = *(const short8*)&Qh[(size_t)qrow * KD + 32 + g * 8];

  float m = -1e30f, l = 0.0f;
  floatx4 accO[4] = {};

  // stage K tile into Kbuf[buf] (8KB, linear both sides)
  auto stage_k = [&](int buf, int tile) {
#pragma unroll
    for (int i = 0; i < 2; ++i) {
      __builtin_amdgcn_global_load_lds(
          (const __attribute__((address_space(1))) void*)(Kh + (size_t)tile * 4096 + i * 2048 + tid * 8),
          (__attribute__((address_space(3))) void*)((char*)&Kbuf[buf][0] + i * 4096 + w * 1024),
          16, 0, 0);
    }
  };

  stage_k(0, 0);
  __syncthreads();

  for (int t = 0; t < NT; ++t) {
    int cur = t & 1;
    const char* kb = (const char*)&Kbuf[cur][0];

    // K fragments from LDS (lane-linear b128, conflict-free)
    short8 kf[4][2];
#pragma unroll
    for (int tt = 0; tt < 4; ++tt)
#pragma unroll
      for (int hf = 0; hf < 2; ++hf)
        kf[tt][hf] = *(const short8*)(kb + tt * 2048 + hf * 1024 + lane * 16);

    // V fragments from global (blocked: contiguous 1KB per load, L1/L2-hit)
    short8 vf[2][4];
    const uint16_t* vtile = Vh + (size_t)t * 4096;
#pragma unroll
    for (int c = 0; c < 2; ++c)
#pragma unroll
      for (int dt = 0; dt < 4; ++dt)
        vf[c][dt] = *(const short8*)&vtile[(c * 4 + dt) * 512 + lane * 8];

    // prefetch next K tile (issued last so the vf wait is a counted vmcnt)
    stage_k(cur ^ 1, (t + 1 < NT) ? (t + 1) : t);

    // S^T = K @ Q^T : lane (c16=q) holds kv = tt*16 + g*4 + r
    floatx4 sacc[4] = {};
#pragma unroll
    for (int tt = 0; tt < 4; ++tt) {
      sacc[tt] = MFMA16(kf[tt][0], qf0, sacc[tt]);
      sacc[tt] = MFMA16(kf[tt][1], qf1, sacc[tt]);
    }

    // ---- online softmax, kv-reduce mostly in-register (2-deep shfl chain) ----
    float mt0 = fmaxf(fmaxf(sacc[0][0], sacc[0][1]), fmaxf(sacc[0][2], sacc[0][3]));
    float mt1 = fmaxf(fmaxf(sacc[1][0], sacc[1][1]), fmaxf(sacc[1][2], sacc[1][3]));
    float mt2 = fmaxf(fmaxf(sacc[2][0], sacc[2][1]), fmaxf(sacc[2][2], sacc[2][3]));
    float mt3 = fmaxf(fmaxf(sacc[3][0], sacc[3][1]), fmaxf(sacc[3][2], sacc[3][3]));
    float mx = fmaxf(fmaxf(mt0, mt1), fmaxf(mt2, mt3));
    mx = fmaxf(mx, __shfl_xor(mx, 16));
    mx = fmaxf(mx, __shfl_xor(mx, 32));
    float nm = fmaxf(m, mx);
    float al = exp2f(m - nm);
    m = nm;
    float ss = 0.0f;
#pragma unroll
    for (int tt = 0; tt < 4; ++tt) {
#pragma unroll
      for (int r = 0; r < 4; ++r)
        sacc[tt][r] = exp2f(sacc[tt][r] - nm);
      ss += (sacc[tt][0] + sacc[tt][1]) + (sacc[tt][2] + sacc[tt][3]);
    }
    ss += __shfl_xor(ss, 16);
    ss += __shfl_xor(ss, 32);
    l = l * al + ss;

    // alpha for accO rows (q = g*4+r lives in lane g*4+r)
    float av[4];
#pragma unroll
    for (int r = 0; r < 4; ++r) av[r] = __shfl(al, g * 4 + r);
#pragma unroll
    for (int dt = 0; dt < 4; ++dt)
#pragma unroll
      for (int r = 0; r < 4; ++r) accO[dt][r] *= av[r];

    // ---- pack P -> LDS (b64 writes), read PV A-frags (b128), wave-private ----
#pragma unroll
    for (int tt = 0; tt < 4; ++tt) {
      uint32_t w0 = (uint32_t)f2bf(sacc[tt][0]) | ((uint32_t)f2bf(sacc[tt][1]) << 16);
      uint32_t w1 = (uint32_t)f2bf(sacc[tt][2]) | ((uint32_t)f2bf(sacc[tt][3]) << 16);
      *(uint2*)&Plds[w][c16][tt * 16 + g * 4] = make_uint2(w0, w1);
    }
#pragma unroll
    for (int c = 0; c < 2; ++c) {
      short8 pa = *(const short8*)&Plds[w][c16][c * 32 + g * 8];
#pragma unroll
      for (int dt = 0; dt < 4; ++dt)
        accO[dt] = MFMA16(pa, vf[c][dt], accO[dt]);
    }

    __syncthreads();  // next-tile K staged; all waves done with Kbuf[cur]
  }

  // ---- normalize + store O in (b, s, h*64+d) layout ----
  float lv[4];
#pragma unroll
  for (int r = 0; r < 4; ++r) lv[r] = 1.0f / __shfl(l, g * 4 + r);
#pragma unroll
  for (int dt = 0; dt < 4; ++dt) {
#pragma unroll
    for (int r = 0; r < 4; ++r) {
      int s = qb + w * 16 + g * 4 + r;
      int d = dt * 16 + c16;
      O[((size_t)(b * SQ + s)) * DM + h * KD + d] = f2bf(accO[dt][r] * lv[r]);
    }
  }
}

// ---------------- launch ----------------
extern "C" void kernel_launch(void* const* d_in, const int* in_sizes, int n_in,
                              void* d_out, int out_size, void* d_ws, size_t ws_size,
                              hipStream_t stream) {
  const float* X = (const float*)d_in[0];
  const float* Wq = (const float*)d_in[1];
  const float* Wk = (const float*)d_in[2];
  const float* Wv = (const float*)d_in[3];
  const float* Wo = (const float*)d_in[4];
  float* out = (float*)d_out;

  char* ws = (char*)d_ws;
  uint16_t* Xb    = (uint16_t*)(ws);                 //  8 MiB  [4096][1024]
  uint16_t* Wqkvb = (uint16_t*)(ws + 8388608);       //  6 MiB  [3072][1024]
  uint16_t* Wob   = (uint16_t*)(ws + 14680064);      //  2 MiB  [1024][1024]
  uint16_t* Qb    = (uint16_t*)(ws + 16777216);      //  8 MiB  (bh,s,d)
  uint16_t* Kb    = (uint16_t*)(ws + 25165824);      //  8 MiB  blocked
  uint16_t* VTb   = (uint16_t*)(ws + 33554432);      //  8 MiB  blocked
  uint16_t* Ob    = (uint16_t*)(ws + 41943040);      //  8 MiB  [4096][1024]

  hipLaunchKernelGGL(convert_kernel, dim3(1024), dim3(256), 0, stream,
                     X, Wq, Wk, Wv, Wo, Xb, Wqkvb, Wob);
  hipLaunchKernelGGL((gemm_bt<0>), dim3(32 * 24), dim3(256), 0, stream,
                     Xb, Wqkvb, 24, Qb, Kb, VTb, nullptr);
  hipLaunchKernelGGL(attn_kernel, dim3(1024), dim3(256), 0, stream,
                     Qb, Kb, VTb, Ob);
  hipLaunchKernelGGL((gemm_bt<1>), dim3(32 * 8), dim3(256), 0, stream,
                     Ob, Wob, 8, nullptr, nullptr, nullptr, out);
}

// Round 3
// 215.429 us; speedup vs baseline: 1.7310x; 1.0476x over previous
//
#include <hip/hip_runtime.h>
#include <hip/hip_bf16.h>
#include <stdint.h>

typedef __attribute__((ext_vector_type(8))) short short8;
typedef __attribute__((ext_vector_type(4))) float floatx4;

#define MFMA16(a, b, c) __builtin_amdgcn_mfma_f32_16x16x32_bf16((a), (b), (c), 0, 0, 0)

static __device__ __forceinline__ uint16_t f2bf(float f) {
  union { float f; uint32_t u; } x; x.f = f;
  uint32_t r = x.u + 0x7fffu + ((x.u >> 16) & 1u);
  return (uint16_t)(r >> 16);
}

static __device__ __forceinline__ uint32_t cvtpk_bf16(float lo, float hi) {
  uint32_t r;
  asm("v_cvt_pk_bf16_f32 %0, %1, %2" : "=v"(r) : "v"(lo), "v"(hi));
  return r;
}

constexpr int DM = 1024, NH = 16, KD = 64, NB = 2, SQ = 2048;
constexpr int MTOT = NB * SQ;  // 4096
constexpr int NT = SQ / 64;    // 32 kv tiles

// ---------------- kernel 1: fp32 -> bf16 convert ----------------
__global__ void convert_kernel(const float* __restrict__ X,
                               const float* __restrict__ Wq, const float* __restrict__ Wk,
                               const float* __restrict__ Wv, const float* __restrict__ Wo,
                               uint16_t* __restrict__ Xb, uint16_t* __restrict__ Wqkvb,
                               uint16_t* __restrict__ Wob) {
  const int NX = MTOT * DM;   // 4194304
  const int NW = DM * DM;     // 1048576
  const int TOT8 = (NX + 4 * NW) / 8;
  for (int t = blockIdx.x * blockDim.x + threadIdx.x; t < TOT8; t += gridDim.x * blockDim.x) {
    int i = t * 8;
    const float* src; uint16_t* dst;
    if (i < NX) { src = X + i; dst = Xb + i; }
    else if (i < NX + 3 * NW) {
      int j = i - NX; dst = Wqkvb + j;
      src = (j < NW) ? (Wq + j) : (j < 2 * NW) ? (Wk + (j - NW)) : (Wv + (j - 2 * NW));
    } else {
      int j = i - NX - 3 * NW; src = Wo + j; dst = Wob + j;
    }
    float4 a = ((const float4*)src)[0];
    float4 b = ((const float4*)src)[1];
    ushort4 o0, o1;
    o0.x = f2bf(a.x); o0.y = f2bf(a.y); o0.z = f2bf(a.z); o0.w = f2bf(a.w);
    o1.x = f2bf(b.x); o1.y = f2bf(b.y); o1.z = f2bf(b.z); o1.w = f2bf(b.w);
    ((ushort4*)dst)[0] = o0;
    ((ushort4*)dst)[1] = o1;
  }
}

// ---------------- kernel 2/4: 128x128 bf16 GEMM, C = A @ B^T ----------------
// MODE 0: QKV epilogue -> Q (bh,s,d)*0.125*log2e ; K blocked frag-linear ; V pi-permuted blocked
// MODE 1: plain fp32 store to Out[M][1024]
template <int MODE>
__global__ __launch_bounds__(256) void gemm_bt(const uint16_t* __restrict__ Aq,
                                               const uint16_t* __restrict__ Bq, int Ntiles,
                                               uint16_t* __restrict__ Qb, uint16_t* __restrict__ Kb,
                                               uint16_t* __restrict__ VTb, float* __restrict__ Out) {
  __shared__ uint16_t Al[128 * 32];
  __shared__ uint16_t Bl[128 * 32];
  const int K = 1024;
  // XCD-aware swizzle (grid % 8 == 0 in both modes -> bijective)
  int nwg = gridDim.x;
  int bid = (blockIdx.x & 7) * (nwg >> 3) + (blockIdx.x >> 3);
  int bm = bid / Ntiles, bn = bid % Ntiles;
  int brow = bm * 128, bcol = bn * 128;
  int tid = threadIdx.x;
  int w = tid >> 6, lane = tid & 63, g = lane >> 4, c16 = lane & 15;
  int wm = w >> 1, wn = w & 1;
  int rr = tid >> 2;            // 0..63 row within 64-row half-tile
  int ce = (tid & 3) * 8;       // col element (8 bf16 = 16B)

  floatx4 acc[4][4] = {};

  for (int k0 = 0; k0 < K; k0 += 32) {
    __syncthreads();
#pragma unroll
    for (int c = 0; c < 2; ++c) {
      __builtin_amdgcn_global_load_lds(
          (const __attribute__((address_space(1))) void*)(Aq + (size_t)(brow + c * 64 + rr) * K + k0 + ce),
          (__attribute__((address_space(3))) void*)((char*)Al + c * 4096 + w * 1024), 16, 0, 0);
      __builtin_amdgcn_global_load_lds(
          (const __attribute__((address_space(1))) void*)(Bq + (size_t)(bcol + c * 64 + rr) * K + k0 + ce),
          (__attribute__((address_space(3))) void*)((char*)Bl + c * 4096 + w * 1024), 16, 0, 0);
    }
    __syncthreads();
    short8 af[4], bf[4];
#pragma unroll
    for (int mt = 0; mt < 4; ++mt)
      af[mt] = *(const short8*)&Al[(wm * 64 + mt * 16 + c16) * 32 + g * 8];
#pragma unroll
    for (int nt = 0; nt < 4; ++nt)
      bf[nt] = *(const short8*)&Bl[(wn * 64 + nt * 16 + c16) * 32 + g * 8];
#pragma unroll
    for (int mt = 0; mt < 4; ++mt)
#pragma unroll
      for (int nt = 0; nt < 4; ++nt)
        acc[mt][nt] = MFMA16(af[mt], bf[nt], acc[mt][nt]);
  }

#pragma unroll
  for (int mt = 0; mt < 4; ++mt) {
#pragma unroll
    for (int nt = 0; nt < 4; ++nt) {
      int n = bcol + wn * 64 + nt * 16 + c16;
#pragma unroll
      for (int r = 0; r < 4; ++r) {
        int m = brow + wm * 64 + mt * 16 + g * 4 + r;
        float v = acc[mt][nt][r];
        if (MODE == 0) {
          int proj = n >> 10;
          int hd = n & 1023;
          int h = hd >> 6, d = hd & 63;
          int b = m >> 11, s = m & 2047;
          size_t bh = (size_t)(b * NH + h);
          if (proj == 0) {
            // fold 1/sqrt(64) * log2(e) so attention can use exp2 directly
            Qb[(bh * SQ + s) * KD + d] = f2bf(v * 0.18033688011112042f);
          } else if (proj == 1) {
            // K blocked frag-linear: elem = st*1024 + k8*128 + r2*8 + j
            int st = s >> 4, r2 = s & 15, k8 = d >> 3, j = d & 7;
            Kb[bh * (size_t)(SQ * KD) + (((size_t)(st * 8 + k8) * 16 + r2) * 8 + j)] = f2bf(v);
          } else {
            // V pi-permuted blocked per 64-kv tile:
            // kv_local -> (c = kv>>5, tth = (kv>>4)&1, gg = (kv>>2)&3, rs = kv&3), j' = tth*4+rs
            // addr = kt*4096 + (c*4+dt)*512 + gg*128 + cc*8 + j'
            int kt = s >> 6, kvl = s & 63;
            int c = kvl >> 5, tth = (kvl >> 4) & 1, gg = (kvl >> 2) & 3, rs = kvl & 3;
            int jp = tth * 4 + rs;
            int dt = d >> 4, cc = d & 15;
            VTb[bh * (size_t)(SQ * KD) + (size_t)kt * 4096 +
                (size_t)((c * 4 + dt) * 512 + gg * 128 + cc * 8 + jp)] = f2bf(v);
          }
        } else {
          Out[(size_t)m * DM + n] = v;
        }
      }
    }
  }
}

// ---------------- kernel 3: flash attention (no LDS, no barriers) ----------------
// Q: (bh,s,64) bf16 pre-scaled by 0.125*log2e. K frag-linear blocked; V pi-permuted blocked.
// Grid: 1024 blocks (bh = bid&31 -> same-head blocks share an XCD L2), 256 thr = 4 waves x 16 q.
__global__ __launch_bounds__(256, 4) void attn_kernel(const uint16_t* __restrict__ Q,
                                                      const uint16_t* __restrict__ Kt,
                                                      const uint16_t* __restrict__ Vt,
                                                      uint16_t* __restrict__ O) {
  int bid = blockIdx.x;
  int bh = bid & 31, qt = bid >> 5;
  int qb = qt * 64;
  int b = bh >> 4, h = bh & 15;
  int tid = threadIdx.x, w = tid >> 6, lane = tid & 63, g = lane >> 4, c16 = lane & 15;

  const uint16_t* Qh = Q + (size_t)bh * SQ * KD;
  const uint16_t* Kh = Kt + (size_t)bh * SQ * KD;
  const uint16_t* Vh = Vt + (size_t)bh * SQ * KD;

  int qrow = qb + w * 16 + c16;
  short8 qf0 = *(const short8*)&Qh[(size_t)qrow * KD + g * 8];
  short8 qf1 = *(const short8*)&Qh[(size_t)qrow * KD + 32 + g * 8];

  float m = -1e30f, l = 0.0f;
  floatx4 accO[4] = {};

  // K tile -> regs (frag-linear: 1KB-contiguous per load, L2-hit)
  short8 kfb[2][4][2];
#define LOADK(buf, tile)                                                              \
  {                                                                                   \
    const uint16_t* kt_ = Kh + (size_t)(tile) * 4096;                                 \
    _Pragma("unroll") for (int tt = 0; tt < 4; ++tt)                                  \
        _Pragma("unroll") for (int hf = 0; hf < 2; ++hf)                              \
            kfb[buf][tt][hf] = *(const short8*)&kt_[tt * 1024 + hf * 512 + lane * 8]; \
  }

  LOADK(0, 0);

#pragma unroll 2
  for (int t = 0; t < NT; ++t) {
    int cur = t & 1;

    // V fragments for tile t (pi-permuted blocked: contiguous, consumed ~300cy later)
    short8 vf[2][4];
    const uint16_t* vtile = Vh + (size_t)t * 4096;
#pragma unroll
    for (int c = 0; c < 2; ++c)
#pragma unroll
      for (int dt = 0; dt < 4; ++dt)
        vf[c][dt] = *(const short8*)&vtile[(c * 4 + dt) * 512 + lane * 8];

    // S^T = K @ Q^T : lane (c16=q-col) holds kv = tt*16 + g*4 + r
    floatx4 sacc[4] = {};
#pragma unroll
    for (int tt = 0; tt < 4; ++tt) {
      sacc[tt] = MFMA16(kfb[cur][tt][0], qf0, sacc[tt]);
      sacc[tt] = MFMA16(kfb[cur][tt][1], qf1, sacc[tt]);
    }

    // prefetch next K tile (no deps -> overlaps softmax+PV)
    LOADK(cur ^ 1, (t + 1 < NT) ? (t + 1) : t);

    // ---- online softmax with defer-rescale (THR = 8 in log2 domain) ----
    float mx = fmaxf(fmaxf(fmaxf(sacc[0][0], sacc[0][1]), fmaxf(sacc[0][2], sacc[0][3])),
                     fmaxf(fmaxf(sacc[1][0], sacc[1][1]), fmaxf(sacc[1][2], sacc[1][3])));
    mx = fmaxf(mx, fmaxf(fmaxf(fmaxf(sacc[2][0], sacc[2][1]), fmaxf(sacc[2][2], sacc[2][3])),
                         fmaxf(fmaxf(sacc[3][0], sacc[3][1]), fmaxf(sacc[3][2], sacc[3][3]))));
    mx = fmaxf(mx, __shfl_xor(mx, 16));
    mx = fmaxf(mx, __shfl_xor(mx, 32));
    if (!__all(mx <= m + 8.0f)) {
      float nm = fmaxf(m, mx);
      float al = exp2f(m - nm);
      m = nm;
      l *= al;
      float av[4];
#pragma unroll
      for (int r = 0; r < 4; ++r) av[r] = __shfl(al, g * 4 + r);
#pragma unroll
      for (int dt = 0; dt < 4; ++dt)
#pragma unroll
        for (int r = 0; r < 4; ++r) accO[dt][r] *= av[r];
    }
    float ss = 0.0f;
#pragma unroll
    for (int tt = 0; tt < 4; ++tt) {
#pragma unroll
      for (int r = 0; r < 4; ++r)
        sacc[tt][r] = exp2f(sacc[tt][r] - m);
      ss += (sacc[tt][0] + sacc[tt][1]) + (sacc[tt][2] + sacc[tt][3]);
    }
    ss += __shfl_xor(ss, 16);
    ss += __shfl_xor(ss, 32);
    l += ss;

    // ---- P pack (pure-local thanks to pi-permuted V) + PV ----
    union { uint32_t u[4]; short8 s8; } pa[2];
#pragma unroll
    for (int c = 0; c < 2; ++c) {
      pa[c].u[0] = cvtpk_bf16(sacc[2 * c][0], sacc[2 * c][1]);
      pa[c].u[1] = cvtpk_bf16(sacc[2 * c][2], sacc[2 * c][3]);
      pa[c].u[2] = cvtpk_bf16(sacc[2 * c + 1][0], sacc[2 * c + 1][1]);
      pa[c].u[3] = cvtpk_bf16(sacc[2 * c + 1][2], sacc[2 * c + 1][3]);
    }
#pragma unroll
    for (int c = 0; c < 2; ++c)
#pragma unroll
      for (int dt = 0; dt < 4; ++dt)
        accO[dt] = MFMA16(pa[c].s8, vf[c][dt], accO[dt]);
  }
#undef LOADK

  // ---- normalize + store O in (b, s, h*64+d) layout ----
  float lv[4];
#pragma unroll
  for (int r = 0; r < 4; ++r) lv[r] = 1.0f / __shfl(l, g * 4 + r);
#pragma unroll
  for (int dt = 0; dt < 4; ++dt) {
#pragma unroll
    for (int r = 0; r < 4; ++r) {
      int s = qb + w * 16 + g * 4 + r;
      int d = dt * 16 + c16;
      O[((size_t)(b * SQ + s)) * DM + h * KD + d] = f2bf(accO[dt][r] * lv[r]);
    }
  }
}

// ---------------- launch ----------------
extern "C" void kernel_launch(void* const* d_in, const int* in_sizes, int n_in,
                              void* d_out, int out_size, void* d_ws, size_t ws_size,
                              hipStream_t stream) {
  const float* X = (const float*)d_in[0];
  const float* Wq = (const float*)d_in[1];
  const float* Wk = (const float*)d_in[2];
  const float* Wv = (const float*)d_in[3];
  const float* Wo = (const float*)d_in[4];
  float* out = (float*)d_out;

  char* ws = (char*)d_ws;
  uint16_t* Xb    = (uint16_t*)(ws);                 //  8 MiB  [4096][1024]
  uint16_t* Wqkvb = (uint16_t*)(ws + 8388608);       //  6 MiB  [3072][1024]
  uint16_t* Wob   = (uint16_t*)(ws + 14680064);      //  2 MiB  [1024][1024]
  uint16_t* Qb    = (uint16_t*)(ws + 16777216);      //  8 MiB  (bh,s,d)
  uint16_t* Kb    = (uint16_t*)(ws + 25165824);      //  8 MiB  blocked
  uint16_t* VTb   = (uint16_t*)(ws + 33554432);      //  8 MiB  pi-permuted blocked
  uint16_t* Ob    = (uint16_t*)(ws + 41943040);      //  8 MiB  [4096][1024]

  hipLaunchKernelGGL(convert_kernel, dim3(1024), dim3(256), 0, stream,
                     X, Wq, Wk, Wv, Wo, Xb, Wqkvb, Wob);
  hipLaunchKernelGGL((gemm_bt<0>), dim3(32 * 24), dim3(256), 0, stream,
                     Xb, Wqkvb, 24, Qb, Kb, VTb, nullptr);
  hipLaunchKernelGGL(attn_kernel, dim3(1024), dim3(256), 0, stream,
                     Qb, Kb, VTb, Ob);
  hipLaunchKernelGGL((gemm_bt<1>), dim3(32 * 8), dim3(256), 0, stream,
                     Ob, Wob, 8, nullptr, nullptr, nullptr, out);
}